// Round 1
// baseline (684.543 us; speedup 1.0000x reference)
//
#include <hip/hip_runtime.h>
#include <hip/hip_bf16.h>

// ---------------- types ----------------
typedef unsigned short u16;
typedef u16   u16x4 __attribute__((ext_vector_type(4)));
typedef u16   u16x8 __attribute__((ext_vector_type(8)));
typedef short s16x8 __attribute__((ext_vector_type(8)));
typedef float f32x4 __attribute__((ext_vector_type(4)));

// Problem constants
#define NB   64
#define NL   512
#define ND   512
#define NA   8
#define K2   1024        // 2*D
#define MROWS 32768      // B*L

__device__ __forceinline__ float b2f(u16 u) {
    unsigned int x = ((unsigned int)u) << 16;
    return __uint_as_float(x);
}
__device__ __forceinline__ u16 f2b(float f) {
    unsigned int x = __float_as_uint(f);
    unsigned int r = (x + 0x7fffu + ((x >> 16) & 1u)) >> 16;
    return (u16)r;
}

// permuted column position for original k within a 64-col K-block:
// stored order puts each lane's 8 MFMA elements contiguous:
// c = (kk*4+g)*8 + (e&3) + 4*(e>>2)  where k = kk*32 + 4g + (e&3) + 16*(e>>2)
__device__ __forceinline__ int permc(int k) {
    int ks  = k >> 6;
    int kr  = k & 63;
    int kk  = kr >> 5;
    int k32 = kr & 31;
    int h   = k32 >> 4;
    int rem = k32 & 15;
    int g   = rem >> 2;
    int e0  = rem & 3;
    return ks * 64 + kk * 32 + g * 8 + h * 4 + e0;
}

__device__ __forceinline__ void gload16(const u16* g, u16* l) {
    __builtin_amdgcn_global_load_lds(
        (const __attribute__((address_space(1))) unsigned int*)g,
        (__attribute__((address_space(3))) unsigned int*)l, 16, 0, 0);
}

// ---------------- kernel 1: build permuted bf16 Batch [32768][1024] ----------------
__global__ void build_batch(const float* __restrict__ H, const float* __restrict__ U,
                            u16* __restrict__ Bt) {
    size_t stride = (size_t)gridDim.x * blockDim.x;
    for (size_t idx = (size_t)blockIdx.x * blockDim.x + threadIdx.x;
         idx < (size_t)MROWS * 256; idx += stride) {
        int r  = (int)(idx >> 8);
        int c  = ((int)idx & 255) << 2;       // permuted col (multiple of 4)
        int ks = c >> 6;
        int w64 = c & 63;
        int cq = w64 >> 3;
        int h  = (w64 >> 2) & 1;
        int kbase = ks * 64 + (cq >> 2) * 32 + (cq & 3) * 4 + h * 16;
        const float* src;
        if (kbase < ND) src = H + (size_t)r * ND + kbase;
        else { int b = r >> 9; src = U + (size_t)b * ND + (kbase - ND); }
        f32x4 v = *(const f32x4*)src;
        u16x4 o;
        o[0] = f2b(v[0]); o[1] = f2b(v[1]); o[2] = f2b(v[2]); o[3] = f2b(v[3]);
        *(u16x4*)(Bt + (size_t)r * K2 + c) = o;
    }
}

// ---------------- kernel 2: W (A,1024,512) f32 -> Wt (A,512,1024) bf16 permuted ----------------
__global__ void build_wt(const float* __restrict__ Wmf, const float* __restrict__ Wpf,
                         u16* __restrict__ Wm, u16* __restrict__ Wp) {
    __shared__ float ld[32][65];
    int bid = blockIdx.x;
    int kt  = bid & 31;
    int dt  = (bid >> 5) & 7;
    int a   = (bid >> 8) & 7;
    int mat = bid >> 11;
    const float* W = mat ? Wpf : Wmf;
    u16* Wt = mat ? Wp : Wm;
    int k0 = kt * 32, d0 = dt * 64;
    int t = threadIdx.x;
    #pragma unroll
    for (int it = 0; it < 8; ++it) {
        int lin = it * 256 + t;
        int i = lin >> 6, j = lin & 63;
        ld[i][j] = W[((size_t)a * K2 + k0 + i) * ND + d0 + j];
    }
    __syncthreads();
    #pragma unroll
    for (int it = 0; it < 8; ++it) {
        int lin = it * 256 + t;
        int dl = lin >> 5, kl = lin & 31;
        int k = k0 + kl;
        Wt[((size_t)a * ND + d0 + dl) * K2 + permc(k)] = f2b(ld[kl][dl]);
    }
}

// ---------------- kernel 3: fused dual GEMM + gate + item write ----------------
// tile 128x128, BK=64, 4 waves (2x2), two accumulators (map & proj)
__global__ __launch_bounds__(256, 2) void gemm_k(
    const u16* __restrict__ Bt, const u16* __restrict__ Wm, const u16* __restrict__ Wp,
    const float* __restrict__ bm, const float* __restrict__ bp,
    u16* __restrict__ item, int a0, int nwg) {
    __shared__ u16 As[128 * 64];
    __shared__ u16 Bms[128 * 64];
    __shared__ u16 Bps[128 * 64];

    int bid = blockIdx.x;
    int chunk = nwg >> 3;                       // XCD-aware swizzle (nwg % 8 == 0)
    int b = (bid & 7) * chunk + (bid >> 3);
    int nt = b & 3;
    int mt = (b >> 2) & 255;
    int al = b >> 10;                           // aspect local to this launch
    int a  = a0 + al;

    int tid = threadIdx.x;
    int lane = tid & 63;
    int w = tid >> 6;
    int wr = w >> 1, wc = w & 1;
    int g = lane >> 4, r15 = lane & 15;

    f32x4 accM[4][4], accP[4][4];
    #pragma unroll
    for (int i = 0; i < 4; ++i)
        #pragma unroll
        for (int j = 0; j < 4; ++j) { accM[i][j] = 0.0f; accP[i][j] = 0.0f; }

    const u16* Abase = Bt + (size_t)(mt * 128) * K2;
    const u16* Mbase = Wm + ((size_t)a * ND + nt * 128) * K2;
    const u16* Pbase = Wp + ((size_t)a * ND + nt * 128) * K2;

    for (int ks = 0; ks < 16; ++ks) {
        __syncthreads();
        #pragma unroll
        for (int it = 0; it < 4; ++it) {
            int slot = it * 256 + tid;
            int row = slot >> 3, sl = slot & 7;
            int q = sl ^ (row & 7);             // inverse-swizzled source slot
            int coff = ks * 64 + q * 8;
            gload16(Abase + (size_t)row * K2 + coff, &As[slot * 8]);
            gload16(Mbase + (size_t)row * K2 + coff, &Bms[slot * 8]);
            gload16(Pbase + (size_t)row * K2 + coff, &Bps[slot * 8]);
        }
        __syncthreads();
        #pragma unroll
        for (int kk = 0; kk < 2; ++kk) {
            s16x8 af[4], fmv[4], fpv[4];
            #pragma unroll
            for (int f = 0; f < 4; ++f) {
                int row = wr * 64 + f * 16 + r15;
                int slot = (kk * 4 + g) ^ (row & 7);
                af[f] = *(const s16x8*)&As[row * 64 + slot * 8];
            }
            #pragma unroll
            for (int f = 0; f < 4; ++f) {
                int row = wc * 64 + f * 16 + r15;
                int slot = (kk * 4 + g) ^ (row & 7);
                fmv[f] = *(const s16x8*)&Bms[row * 64 + slot * 8];
                fpv[f] = *(const s16x8*)&Bps[row * 64 + slot * 8];
            }
            #pragma unroll
            for (int i = 0; i < 4; ++i)
                #pragma unroll
                for (int j = 0; j < 4; ++j) {
                    accM[i][j] = __builtin_amdgcn_mfma_f32_16x16x32_bf16(af[i], fmv[j], accM[i][j], 0, 0, 0);
                    accP[i][j] = __builtin_amdgcn_mfma_f32_16x16x32_bf16(af[i], fpv[j], accP[i][j], 0, 0, 0);
                }
        }
    }

    // epilogue: bias + sigmoid gate, write item bf16
    #pragma unroll
    for (int fn = 0; fn < 4; ++fn) {
        int col = nt * 128 + wc * 64 + fn * 16 + r15;
        float bmv = bm[a * ND + col];
        float bpv = bp[a * ND + col];
        #pragma unroll
        for (int fm = 0; fm < 4; ++fm) {
            int rowb = mt * 128 + wr * 64 + fm * 16 + g * 4;
            #pragma unroll
            for (int j = 0; j < 4; ++j) {
                float m = accM[fm][fn][j] + bmv;
                float p = accP[fm][fn][j] + bpv;
                float gate = 1.0f / (1.0f + __expf(-m));
                item[((size_t)al * MROWS + rowb + j) * ND + col] = f2b(gate * p);
            }
        }
    }
}

// ---------------- kernel 4: scores + softmax(L) + weighted sum ----------------
// one block per (b', a'); item rows R' = bl*4096 + 8*l' + a'
__global__ __launch_bounds__(512) void attn_out_k(
    const u16* __restrict__ item, const float* __restrict__ asp,
    float* __restrict__ out, int b0) {
    __shared__ float asp_s[512];
    __shared__ float attn[512];
    __shared__ float red[4][512];
    int t = threadIdx.x;
    int bl = blockIdx.x >> 3;
    int ap = blockIdx.x & 7;
    int bg = b0 + bl;

    asp_s[t] = asp[ap * ND + t];
    __syncthreads();

    // scores: each thread does one l' row (dot over D)
    const u16* rp = item + ((size_t)bl * 4096 + (size_t)t * 8 + ap) * ND;
    float s = 0.0f;
    for (int j = 0; j < 64; ++j) {
        u16x8 v = *(const u16x8*)(rp + j * 8);
        #pragma unroll
        for (int e = 0; e < 8; ++e) s += b2f(v[e]) * asp_s[j * 8 + e];
    }
    red[0][t] = s;
    __syncthreads();
    for (int off = 256; off > 0; off >>= 1) {
        if (t < off) red[0][t] = fmaxf(red[0][t], red[0][t + off]);
        __syncthreads();
    }
    float mx = red[0][0];
    __syncthreads();
    float p = __expf(s - mx);
    red[0][t] = p;
    __syncthreads();
    for (int off = 256; off > 0; off >>= 1) {
        if (t < off) red[0][t] += red[0][t + off];
        __syncthreads();
    }
    float inv = 1.0f / red[0][0];
    attn[t] = p * inv;
    __syncthreads();

    // weighted sum: 4 l'-groups x 128 d-threads (4 d each)
    int gq = t >> 7, u = t & 127;
    float a0v = 0.f, a1v = 0.f, a2v = 0.f, a3v = 0.f;
    const u16* base2 = item + ((size_t)bl * 4096 + ap) * ND + 4 * u;
    for (int l = gq; l < 512; l += 4) {
        float wv = attn[l];
        u16x4 v = *(const u16x4*)(base2 + (size_t)l * 8 * ND);
        a0v += wv * b2f(v[0]); a1v += wv * b2f(v[1]);
        a2v += wv * b2f(v[2]); a3v += wv * b2f(v[3]);
    }
    red[gq][4 * u + 0] = a0v; red[gq][4 * u + 1] = a1v;
    red[gq][4 * u + 2] = a2v; red[gq][4 * u + 3] = a3v;
    __syncthreads();
    float o = red[0][t] + red[1][t] + red[2][t] + red[3][t];
    out[((size_t)bg * NA + ap) * ND + t] = o;
}

// ---------------- launcher ----------------
extern "C" void kernel_launch(void* const* d_in, const int* in_sizes, int n_in,
                              void* d_out, int out_size, void* d_ws, size_t ws_size,
                              hipStream_t stream) {
    const float* H   = (const float*)d_in[0];
    const float* U   = (const float*)d_in[1];
    const float* asp = (const float*)d_in[2];
    const float* Wmf = (const float*)d_in[3];
    const float* bmf = (const float*)d_in[4];
    const float* Wpf = (const float*)d_in[5];
    const float* bpf = (const float*)d_in[6];
    float* out = (float*)d_out;

    char* ws = (char*)d_ws;
    const size_t BATCH_BYTES = (size_t)MROWS * K2 * 2;        // 64 MB
    const size_t WT_BYTES    = (size_t)NA * ND * K2 * 2;      // 8 MB each
    u16* Bt   = (u16*)(ws);
    u16* Wm   = (u16*)(ws + BATCH_BYTES);
    u16* Wp   = (u16*)(ws + BATCH_BYTES + WT_BYTES);
    u16* item = (u16*)(ws + BATCH_BYTES + 2 * WT_BYTES);
    size_t fixed = BATCH_BYTES + 2 * WT_BYTES;                 // 80 MB
    const size_t ITEM_PER_ASPECT = (size_t)MROWS * ND * 2;     // 32 MB
    size_t avail = (ws_size > fixed) ? (ws_size - fixed) : 0;
    int na = (int)(avail / ITEM_PER_ASPECT);
    if (na > NA) na = NA;
    if (na < 1) na = 1;

    build_batch<<<4096, 256, 0, stream>>>(H, U, Bt);
    build_wt<<<4096, 256, 0, stream>>>(Wmf, Wpf, Wm, Wp);

    for (int a0 = 0; a0 < NA; a0 += na) {
        int n = (na < NA - a0) ? na : (NA - a0);
        gemm_k<<<n * 1024, 256, 0, stream>>>(Bt, Wm, Wp, bmf, bpf, item, a0, n * 1024);
        attn_out_k<<<n * 64, 512, 0, stream>>>(item, asp, out, a0 * 8);
    }
}